// Round 4
// baseline (236.026 us; speedup 1.0000x reference)
//
#include <hip/hip_runtime.h>

// LaneAttention: per-lane MLP score -> per-group(8) softmax -> weighted pool of
// concat(ht, info, future) into out[32768, 192] fp32.
//
// R3: R0/R2 were outstanding-request bound: ~4 loads in flight/wave x 64
// scattered lines x 16 waves/CU / 900cy HBM latency ~= 2.9 TB/s — exactly the
// measured 2.3-2.4 TB/s. Fix: batch ALL 32 phase-1 float4 loads into named
// registers before any FMA, widening the vmcnt window to 32 in-flight
// instructions per wave (~384 outstanding lines/CU at 12 waves/CU -> ~7 TB/s
// ceiling -> HBM-bound). Single-wave 64-thread blocks, zero LDS, zero
// barriers; prob via __shfl; phase-2 pooling coalesced + L2-hot as before.

__global__ __launch_bounds__(64) void lane_attn_kernel(
    const float* __restrict__ ht,     // [M,64]
    const float* __restrict__ info,   // [M,64]
    const float* __restrict__ fut,    // [M,64]
    const float* __restrict__ W1,     // [128,16]
    const float* __restrict__ b1,     // [16]
    const float* __restrict__ W2,     // [16]
    const float* __restrict__ b2,     // [1]
    const int*   __restrict__ seg,    // [M]
    float*       __restrict__ out)    // [N_GROUPS,192]
{
    const int t    = threadIdx.x;     // 0..63, one wave
    const int base = blockIdx.x * 64;
    const int lane = base + t;

    const float4* htp = (const float4*)(ht   + (size_t)lane * 64);
    const float4* inp = (const float4*)(info + (size_t)lane * 64);

    // ---------------- phase 1: batch-load the whole row ----------------
    // 32 dwordx4 loads issued before any consumption -> 32 outstanding vmem
    // per wave. This is the entire point of this revision.
    float4 va[16], vb[16];
#pragma unroll
    for (int k = 0; k < 16; ++k) va[k] = htp[k];
#pragma unroll
    for (int k = 0; k < 16; ++k) vb[k] = inp[k];

    float h[16];
#pragma unroll
    for (int j = 0; j < 16; ++j) h[j] = b1[j];

#pragma unroll
    for (int k4 = 0; k4 < 16; ++k4) {
        const float4 v = va[k4];
#pragma unroll
        for (int j = 0; j < 16; ++j) {
            h[j] = fmaf(v.x, W1[(k4 * 4 + 0) * 16 + j], h[j]);
            h[j] = fmaf(v.y, W1[(k4 * 4 + 1) * 16 + j], h[j]);
            h[j] = fmaf(v.z, W1[(k4 * 4 + 2) * 16 + j], h[j]);
            h[j] = fmaf(v.w, W1[(k4 * 4 + 3) * 16 + j], h[j]);
        }
    }
#pragma unroll
    for (int k4 = 0; k4 < 16; ++k4) {
        const float4 v = vb[k4];
#pragma unroll
        for (int j = 0; j < 16; ++j) {
            h[j] = fmaf(v.x, W1[(64 + k4 * 4 + 0) * 16 + j], h[j]);
            h[j] = fmaf(v.y, W1[(64 + k4 * 4 + 1) * 16 + j], h[j]);
            h[j] = fmaf(v.z, W1[(64 + k4 * 4 + 2) * 16 + j], h[j]);
            h[j] = fmaf(v.w, W1[(64 + k4 * 4 + 3) * 16 + j], h[j]);
        }
    }

    float score = b2[0];
#pragma unroll
    for (int j = 0; j < 16; ++j)
        score = fmaf(fmaxf(h[j], 0.0f), W2[j], score);

    // ---------------- softmax within each 8-lane subgroup ----------------
    float m = score;
    m = fmaxf(m, __shfl_xor(m, 1));
    m = fmaxf(m, __shfl_xor(m, 2));
    m = fmaxf(m, __shfl_xor(m, 4));
    float e = __expf(score - m);
    float s = e;
    s += __shfl_xor(s, 1);
    s += __shfl_xor(s, 2);
    s += __shfl_xor(s, 4);
    const float prob = e / s;   // lane t holds prob of row base+t

    // ---------------- phase 2: softmax-weighted pooling --------------------
    // Wave pools its own 8 groups; thread c covers column c. Coalesced 256B
    // row reads; ht/info L2-hot from phase 1, fut first-touch.
    const int c = t;
    for (int gg = 0; gg < 8; ++gg) {
        const int r0  = base + gg * 8;
        const int gid = seg[r0];          // wave-uniform
        float a0 = 0.0f, a1 = 0.0f, a2 = 0.0f;
#pragma unroll
        for (int i = 0; i < 8; ++i) {
            const float  p = __shfl(prob, gg * 8 + i);
            const size_t r = (size_t)(r0 + i) * 64;
            a0 = fmaf(p, ht[r + c],   a0);
            a1 = fmaf(p, info[r + c], a1);
            a2 = fmaf(p, fut[r + c],  a2);
        }
        float* o = out + (size_t)gid * 192;
        o[c]       = a0;
        o[64 + c]  = a1;
        o[128 + c] = a2;
    }
}

extern "C" void kernel_launch(void* const* d_in, const int* in_sizes, int n_in,
                              void* d_out, int out_size, void* d_ws, size_t ws_size,
                              hipStream_t stream) {
    const float* ht   = (const float*)d_in[0];
    const float* info = (const float*)d_in[1];
    const float* fut  = (const float*)d_in[2];
    const float* W1   = (const float*)d_in[3];
    const float* b1   = (const float*)d_in[4];
    const float* W2   = (const float*)d_in[5];
    const float* b2   = (const float*)d_in[6];
    const int*   seg  = (const int*)d_in[7];
    float*       out  = (float*)d_out;

    const int M = in_sizes[7];           // 262144 lanes
    const int blocks = M / 64;           // 4096 single-wave blocks

    lane_attn_kernel<<<blocks, 64, 0, stream>>>(ht, info, fut, W1, b1, W2, b2,
                                                seg, out);
}